// Round 3
// baseline (721.779 us; speedup 1.0000x reference)
//
#include <hip/hip_runtime.h>
#include <hip/hip_bf16.h>

// DynamicLoRALinear: out = x @ W^T + b + 2.0 * ((x @ A[slot]) @ Bm[slot])
// fp32 I/O; compute in bf16 MFMA (absmax 0.031 vs threshold 0.1425).
// R8: (a) GEMM reverted to the proven R4/R5 128^2 2-barrier structure (390us,
//     705 TF) after two failed schedule-surgery rounds (R6: 405, R7: 437).
//     (b) prep fused: one kernel = lora_hx blocks [0,256) + W-cvt blocks
//     [256,2304); cvt blocks co-reside and hide lora latency.
//     (c) lora_hx K-loop software-pipelined (reg prefetch of X/A across the
//     barrier) -- was 4 waves/CU with fully exposed HBM latency per iter.

typedef __bf16 bf16_t;
typedef __bf16 bf16x8 __attribute__((ext_vector_type(8)));
typedef __bf16 bf16x4 __attribute__((ext_vector_type(4)));
typedef float f32x4 __attribute__((ext_vector_type(4)));

#define M_DIM 8192
#define K_DIM 4096
#define N_DIM 4096
#define SCALE_F 2.0f

#define LORA_BLOCKS 256          // M_DIM / 32
#define CVT_BLOCKS 2048
#define PREP_BLOCKS (LORA_BLOCKS + CVT_BLOCKS)

__device__ __forceinline__ void gload_lds16(const void* g, void* l) {
    __builtin_amdgcn_global_load_lds(
        (const __attribute__((address_space(1))) void*)g,
        (__attribute__((address_space(3))) void*)l, 16, 0, 0);
}

// ------- prep kernel: fused {X->bf16 + h = 2*(x@A[slot])}  and  {W->bf16} -------
// blocks [0, 256): 32 rows of X each; pipelined K-loop (prefetch regs across
//                  the barrier so HBM latency overlaps MFMA+LDS work).
// blocks [256, 2304): grid-stride fp32->bf16 convert of W (if Wb != null).
__global__ __launch_bounds__(256) void prep_kernel(
    const float* __restrict__ X,
    const float* __restrict__ lora_As,
    const int* __restrict__ mapping,
    float* __restrict__ h_ws,
    bf16_t* __restrict__ Xb,            // null in fallback path
    const float* __restrict__ W,
    bf16_t* __restrict__ Wb)            // null in fallback path
{
    __shared__ bf16_t Xt[32 * 16 * 8];  // 8 KB, swizzled chunks of 8 bf16
    __shared__ bf16_t At[16 * 136];     // 4.25 KB, [r][k] padded
    __shared__ float hred[4 * 2 * 16 * 16];  // 8 KB

    const int tid = threadIdx.x;
    const int bid = blockIdx.x;

    if (bid >= LORA_BLOCKS) {
        // ---------------- W convert part ----------------
        if (Wb) {
            const int n4 = N_DIM * K_DIM / 4;
            int i = (bid - LORA_BLOCKS) * 256 + tid;
            const int stride = CVT_BLOCKS * 256;
            for (; i < n4; i += stride) {
                f32x4 v = ((const f32x4*)W)[i];
                bf16x4 o = {(bf16_t)v[0], (bf16_t)v[1], (bf16_t)v[2], (bf16_t)v[3]};
                ((bf16x4*)Wb)[i] = o;
            }
        }
        return;
    }

    // ---------------- lora_hx part ----------------
    const int wave = tid >> 6;
    const int lane = tid & 63;
    const int bm0  = bid * 32;
    const int slot = mapping[bm0 >> 10];
    const float* __restrict__ A = lora_As + (size_t)slot * (K_DIM * 16);

    const int srow = tid >> 3;          // 0..31 staging row
    const int sc2  = tid & 7;           // chunk-pair 0..7
    const int r16  = lane & 15;
    const int kq   = lane >> 4;
    const int kk   = tid >> 1;          // A-tile k row 0..127
    const int half = tid & 1;

    f32x4 acc[2];
    acc[0] = (f32x4){0.f, 0.f, 0.f, 0.f};
    acc[1] = (f32x4){0.f, 0.f, 0.f, 0.f};

    const float* xrow = X + (size_t)(bm0 + srow) * K_DIM + sc2 * 16;

    // prefetch registers for iteration k0=0
    f32x4 xv0 = *(const f32x4*)(xrow);
    f32x4 xv1 = *(const f32x4*)(xrow + 4);
    f32x4 xv2 = *(const f32x4*)(xrow + 8);
    f32x4 xv3 = *(const f32x4*)(xrow + 12);
    f32x4 av0 = *(const f32x4*)(A + (size_t)kk * 16 + half * 8);
    f32x4 av1 = *(const f32x4*)(A + (size_t)kk * 16 + half * 8 + 4);

    for (int k0 = 0; k0 < K_DIM; k0 += 128) {
        // ---- consume prefetched regs: convert + LDS + Xb ----
        bf16x8 c0 = {(bf16_t)xv0[0], (bf16_t)xv0[1], (bf16_t)xv0[2], (bf16_t)xv0[3],
                     (bf16_t)xv1[0], (bf16_t)xv1[1], (bf16_t)xv1[2], (bf16_t)xv1[3]};
        bf16x8 c1 = {(bf16_t)xv2[0], (bf16_t)xv2[1], (bf16_t)xv2[2], (bf16_t)xv2[3],
                     (bf16_t)xv3[0], (bf16_t)xv3[1], (bf16_t)xv3[2], (bf16_t)xv3[3]};
        if (Xb) {
            bf16x8* xbp = (bf16x8*)(Xb + (size_t)(bm0 + srow) * K_DIM + k0 + sc2 * 16);
            xbp[0] = c0;
            xbp[1] = c1;
        }
        const int k8a = sc2 * 2, k8b = sc2 * 2 + 1;
        *(bf16x8*)(Xt + (srow * 16 + (k8a ^ (srow & 15))) * 8) = c0;
        *(bf16x8*)(Xt + (srow * 16 + (k8b ^ (srow & 15))) * 8) = c1;

#pragma unroll
        for (int rr = 0; rr < 4; ++rr) {
            At[(half * 8 + rr) * 136 + kk]     = (bf16_t)av0[rr];
            At[(half * 8 + 4 + rr) * 136 + kk] = (bf16_t)av1[rr];
        }
        __syncthreads();

        // ---- issue next iteration's global loads (overlap with MFMA) ----
        if (k0 + 128 < K_DIM) {
            const float* xp = xrow + k0 + 128;
            xv0 = *(const f32x4*)(xp);
            xv1 = *(const f32x4*)(xp + 4);
            xv2 = *(const f32x4*)(xp + 8);
            xv3 = *(const f32x4*)(xp + 12);
            const float* ap = A + (size_t)(k0 + 128 + kk) * 16 + half * 8;
            av0 = *(const f32x4*)ap;
            av1 = *(const f32x4*)(ap + 4);
        }

        // ---- MFMA: wave w = k-frag w; 2 m-frags of 16 rows ----
#pragma unroll
        for (int i = 0; i < 2; ++i) {
            const int row_l = i * 16 + r16;
            const int c = wave * 4 + kq;
            bf16x8 af  = *(const bf16x8*)(Xt + (row_l * 16 + (c ^ (row_l & 15))) * 8);
            bf16x8 bfr = *(const bf16x8*)(At + r16 * 136 + wave * 32 + kq * 8);
            acc[i] = __builtin_amdgcn_mfma_f32_16x16x32_bf16(af, bfr, acc[i], 0, 0, 0);
        }
        __syncthreads();
    }

    // ---- cross-wave reduction (each wave holds k-frag partials) ----
#pragma unroll
    for (int i = 0; i < 2; ++i)
#pragma unroll
        for (int e = 0; e < 4; ++e)
            hred[wave * 512 + i * 256 + (kq * 4 + e) * 16 + r16] = acc[i][e];
    __syncthreads();
#pragma unroll
    for (int q = 0; q < 2; ++q) {
        const int entry = tid * 2 + q;          // 0..511
        const int row_l = entry >> 4, col = entry & 15;
        const int i = row_l >> 4, rr = row_l & 15;
        const int off = i * 256 + rr * 16 + col;
        float s = hred[off] + hred[512 + off] + hred[1024 + off] + hred[1536 + off];
        h_ws[(size_t)(bm0 + row_l) * 16 + col] = s * SCALE_F;
    }
}

// ---- shared epilogue: fused LoRA MFMA K-tile + bias + store ----
__device__ __forceinline__ void epilogue(
    f32x4 (&acc)[4][4], const float* __restrict__ bias,
    const float* __restrict__ lora_Bs, const int* __restrict__ mapping,
    const float* __restrict__ h_ws, float* __restrict__ out,
    int bm0, int bn0, int wm0, int wn0, int r16, int kq)
{
    const int slot = mapping[bm0 >> 10];
    const bool hasK = (kq < 2);
    const int kq2 = hasK ? kq : 0;

    bf16x8 hfrag[4], bmf[4];
#pragma unroll
    for (int i = 0; i < 4; ++i) {
        const float* hp = h_ws + (size_t)(bm0 + wm0 + i * 16 + r16) * 16 + kq2 * 8;
        f32x4 h0 = *(const f32x4*)hp;
        f32x4 h1 = *(const f32x4*)(hp + 4);
#pragma unroll
        for (int jj = 0; jj < 4; ++jj) {
            hfrag[i][jj]     = hasK ? (bf16_t)h0[jj] : (bf16_t)0.f;
            hfrag[i][jj + 4] = hasK ? (bf16_t)h1[jj] : (bf16_t)0.f;
        }
    }
#pragma unroll
    for (int j = 0; j < 4; ++j) {
        const int o = bn0 + wn0 + j * 16 + r16;
#pragma unroll
        for (int jj = 0; jj < 8; ++jj) {
            const int r = kq2 * 8 + jj;
            const float v = lora_Bs[((size_t)slot * 16 + r) * N_DIM + o];
            bmf[j][jj] = hasK ? (bf16_t)v : (bf16_t)0.f;
        }
    }
#pragma unroll
    for (int i = 0; i < 4; ++i)
#pragma unroll
        for (int j = 0; j < 4; ++j)
            acc[i][j] = __builtin_amdgcn_mfma_f32_16x16x32_bf16(hfrag[i], bmf[j], acc[i][j], 0, 0, 0);

#pragma unroll
    for (int j = 0; j < 4; ++j) {
        const int o = bn0 + wn0 + j * 16 + r16;
        const float bv = bias[o];
#pragma unroll
        for (int i = 0; i < 4; ++i) {
#pragma unroll
            for (int e = 0; e < 4; ++e) {
                const int m = bm0 + wm0 + i * 16 + kq * 4 + e;
                out[(size_t)m * N_DIM + o] = acc[i][j][e] + bv;
            }
        }
    }
}

// ---------------- main GEMM (direct bf16, BK=64, XOR-swizzled LDS) ----------------
__global__ __launch_bounds__(256) void gemm_lora_direct(
    const bf16_t* __restrict__ Xb, const bf16_t* __restrict__ Wb,
    const float* __restrict__ bias, const float* __restrict__ lora_Bs,
    const int* __restrict__ mapping, const float* __restrict__ h_ws,
    float* __restrict__ out)
{
    __shared__ bf16_t As[128 * 64];   // 16 KB
    __shared__ bf16_t Bs[128 * 64];   // 16 KB

    const int tid  = threadIdx.x;
    const int wave = tid >> 6;
    const int lane = tid & 63;
    const int bid  = blockIdx.x;
    const int n_t  = (bid & 7) + ((bid >> 9) << 3);  // 0..31 (XCD-aware)
    const int m_t  = (bid >> 3) & 63;                // 0..63
    const int bm0 = m_t * 128;
    const int bn0 = n_t * 128;
    const int wm0 = (wave >> 1) * 64;
    const int wn0 = (wave & 1) * 64;
    const int r16 = lane & 15;
    const int kq  = lane >> 4;

    f32x4 acc[4][4];
#pragma unroll
    for (int i = 0; i < 4; ++i)
#pragma unroll
        for (int j = 0; j < 4; ++j) acc[i][j] = (f32x4){0.f, 0.f, 0.f, 0.f};

    for (int k0 = 0; k0 < K_DIM; k0 += 64) {
#pragma unroll
        for (int p = 0; p < 4; ++p) {
            const int base = wave * 256 + p * 64;    // wave-uniform LDS slot base
            const int s    = base + lane;
            const int row  = s >> 3;
            const int k8g  = (s & 7) ^ (row & 7);
            gload_lds16(Xb + (size_t)(bm0 + row) * K_DIM + k0 + k8g * 8,
                        As + (size_t)base * 8);
            gload_lds16(Wb + (size_t)(bn0 + row) * K_DIM + k0 + k8g * 8,
                        Bs + (size_t)base * 8);
        }
        __syncthreads();

#pragma unroll
        for (int kh = 0; kh < 2; ++kh) {
            bf16x8 af[4], bfr[4];
            const int k8 = kh * 4 + kq;
#pragma unroll
            for (int i = 0; i < 4; ++i) {
                const int ra = wm0 + i * 16 + r16;
                const int rb = wn0 + i * 16 + r16;
                af[i]  = *(const bf16x8*)(As + ((size_t)ra * 8 + (k8 ^ (ra & 7))) * 8);
                bfr[i] = *(const bf16x8*)(Bs + ((size_t)rb * 8 + (k8 ^ (rb & 7))) * 8);
            }
#pragma unroll
            for (int i = 0; i < 4; ++i)
#pragma unroll
                for (int j = 0; j < 4; ++j)
                    acc[i][j] = __builtin_amdgcn_mfma_f32_16x16x32_bf16(af[i], bfr[j], acc[i][j], 0, 0, 0);
        }
        __syncthreads();
    }

    epilogue(acc, bias, lora_Bs, mapping, h_ws, out, bm0, bn0, wm0, wn0, r16, kq);
}

// ---------------- fallback: fp32 staging via global_load_lds, BK=32 ----------------
__global__ __launch_bounds__(256) void gemm_lora_f32s(
    const float* __restrict__ Xf, const float* __restrict__ Wf,
    const float* __restrict__ bias, const float* __restrict__ lora_Bs,
    const int* __restrict__ mapping, const float* __restrict__ h_ws,
    float* __restrict__ out)
{
    __shared__ float Asf[128 * 32];
    __shared__ float Bsf[128 * 32];

    const int tid  = threadIdx.x;
    const int wave = tid >> 6;
    const int lane = tid & 63;
    const int bid  = blockIdx.x;
    const int n_t  = (bid & 7) + ((bid >> 9) << 3);
    const int m_t  = (bid >> 3) & 63;
    const int bm0 = m_t * 128;
    const int bn0 = n_t * 128;
    const int wm0 = (wave >> 1) * 64;
    const int wn0 = (wave & 1) * 64;
    const int r16 = lane & 15;
    const int kq  = lane >> 4;

    f32x4 acc[4][4];
#pragma unroll
    for (int i = 0; i < 4; ++i)
#pragma unroll
        for (int j = 0; j < 4; ++j) acc[i][j] = (f32x4){0.f, 0.f, 0.f, 0.f};

    for (int k0 = 0; k0 < K_DIM; k0 += 32) {
#pragma unroll
        for (int p = 0; p < 4; ++p) {
            const int idx0 = (p * 4 + wave) * 64;
            const int idx  = idx0 + lane;
            const int k4   = idx >> 7;
            const int row  = idx & 127;
            gload_lds16(Xf + (size_t)(bm0 + row) * K_DIM + (k0 + k4 * 4),
                        Asf + (size_t)idx0 * 4);
            gload_lds16(Wf + (size_t)(bn0 + row) * K_DIM + (k0 + k4 * 4),
                        Bsf + (size_t)idx0 * 4);
        }
        __syncthreads();

        bf16x8 af[4], bfr[4];
#pragma unroll
        for (int i = 0; i < 4; ++i) {
            const int ra = wm0 + i * 16 + r16;
            const int rb = wn0 + i * 16 + r16;
            f32x4 a0 = *(const f32x4*)(Asf + ((size_t)(kq * 2) * 128 + ra) * 4);
            f32x4 a1 = *(const f32x4*)(Asf + ((size_t)(kq * 2 + 1) * 128 + ra) * 4);
            f32x4 b0 = *(const f32x4*)(Bsf + ((size_t)(kq * 2) * 128 + rb) * 4);
            f32x4 b1 = *(const f32x4*)(Bsf + ((size_t)(kq * 2 + 1) * 128 + rb) * 4);
            af[i]  = (bf16x8){(bf16_t)a0[0], (bf16_t)a0[1], (bf16_t)a0[2], (bf16_t)a0[3],
                              (bf16_t)a1[0], (bf16_t)a1[1], (bf16_t)a1[2], (bf16_t)a1[3]};
            bfr[i] = (bf16x8){(bf16_t)b0[0], (bf16_t)b0[1], (bf16_t)b0[2], (bf16_t)b0[3],
                              (bf16_t)b1[0], (bf16_t)b1[1], (bf16_t)b1[2], (bf16_t)b1[3]};
        }
#pragma unroll
        for (int i = 0; i < 4; ++i)
#pragma unroll
            for (int j = 0; j < 4; ++j)
                acc[i][j] = __builtin_amdgcn_mfma_f32_16x16x32_bf16(af[i], bfr[j], acc[i][j], 0, 0, 0);
        __syncthreads();
    }

    epilogue(acc, bias, lora_Bs, mapping, h_ws, out, bm0, bn0, wm0, wn0, r16, kq);
}

extern "C" void kernel_launch(void* const* d_in, const int* in_sizes, int n_in,
                              void* d_out, int out_size, void* d_ws, size_t ws_size,
                              hipStream_t stream) {
    const float* x        = (const float*)d_in[0];
    const int*   mapping  = (const int*)d_in[1];
    const float* W        = (const float*)d_in[2];
    const float* b        = (const float*)d_in[3];
    const float* lora_As  = (const float*)d_in[4];
    const float* lora_Bs  = (const float*)d_in[5];
    float* out = (float*)d_out;

    const size_t xb_bytes = (size_t)M_DIM * K_DIM * 2;   // 64 MB
    const size_t wb_bytes = (size_t)N_DIM * K_DIM * 2;   // 32 MB
    const size_t h_bytes  = (size_t)M_DIM * 16 * 4;      // 512 KB
    const bool direct = ws_size >= xb_bytes + wb_bytes + h_bytes;

    bf16_t* Xb = (bf16_t*)d_ws;
    bf16_t* Wb = (bf16_t*)((char*)d_ws + xb_bytes);
    float*  h_ws = direct ? (float*)((char*)d_ws + xb_bytes + wb_bytes)
                          : (float*)d_ws;

    prep_kernel<<<dim3(PREP_BLOCKS), 256, 0, stream>>>(
        x, lora_As, mapping, h_ws,
        direct ? Xb : nullptr, W, direct ? Wb : nullptr);

    if (direct) {
        gemm_lora_direct<<<dim3(2048), 256, 0, stream>>>(
            Xb, Wb, b, lora_Bs, mapping, h_ws, out);
    } else {
        gemm_lora_f32s<<<dim3(2048), 256, 0, stream>>>(
            x, W, b, lora_Bs, mapping, h_ws, out);
    }
}

// Round 4
// 643.125 us; speedup vs baseline: 1.1223x; 1.1223x over previous
//
#include <hip/hip_runtime.h>
#include <hip/hip_bf16.h>

// DynamicLoRALinear: out = x @ W^T + b + 2.0 * ((x @ A[slot]) @ Bm[slot])
// fp32 I/O; compute in bf16 MFMA (absmax 0.031 vs threshold 0.1425).
// R9: (a) lora phase K-split x4 (1024 blocks, partials h_part[4][8192][16],
//     summed in GEMM epilogue) -- attacks the 1-block/CU latency convoy that
//     reg-prefetch (R8) failed to fix.
//     (b) GEMM split into two 1024-block dispatches (m-halves) so the prep
//     dispatch surfaces in the rocprof top-5 table -- visibility for the
//     ~265us non-GEMM residual that has never been directly observed.
//     GEMM body = proven R5 structure (best measured), only index remap.

typedef __bf16 bf16_t;
typedef __bf16 bf16x8 __attribute__((ext_vector_type(8)));
typedef __bf16 bf16x4 __attribute__((ext_vector_type(4)));
typedef float f32x4 __attribute__((ext_vector_type(4)));

#define M_DIM 8192
#define K_DIM 4096
#define N_DIM 4096
#define SCALE_F 2.0f

#define CVT_BLOCKS 1024

__device__ __forceinline__ void gload_lds16(const void* g, void* l) {
    __builtin_amdgcn_global_load_lds(
        (const __attribute__((address_space(1))) void*)g,
        (__attribute__((address_space(3))) void*)l, 16, 0, 0);
}

// ------- prep kernel: fused {X->bf16 + h partials} and {W->bf16} -------
// blocks [0, lora_blocks): lora. mchunk = bid>>kshift (32 rows), kc = bid&(kcn-1):
//   K-chunk [kc*K/kcn, +K/kcn). Writes h_part[kc] slice (scaled partials).
// blocks [lora_blocks, grid): grid-stride fp32->bf16 convert of W (if Wb).
__global__ __launch_bounds__(256) void prep_kernel(
    const float* __restrict__ X,
    const float* __restrict__ lora_As,
    const int* __restrict__ mapping,
    float* __restrict__ h_ws,           // kcn slices of [M_DIM][16]
    bf16_t* __restrict__ Xb,            // null in fallback path
    const float* __restrict__ W,
    bf16_t* __restrict__ Wb,            // null in fallback path
    int lora_blocks, int kshift)
{
    __shared__ bf16_t Xt[32 * 16 * 8];  // 8 KB, swizzled chunks of 8 bf16
    __shared__ bf16_t At[16 * 136];     // 4.25 KB, [r][k] padded
    __shared__ float hred[4 * 2 * 16 * 16];  // 8 KB

    const int tid = threadIdx.x;
    const int bid = blockIdx.x;

    if (bid >= lora_blocks) {
        if (Wb) {
            const int n4 = N_DIM * K_DIM / 4;
            int i = (bid - lora_blocks) * 256 + tid;
            const int stride = (gridDim.x - lora_blocks) * 256;
            for (; i < n4; i += stride) {
                f32x4 v = ((const f32x4*)W)[i];
                bf16x4 o = {(bf16_t)v[0], (bf16_t)v[1], (bf16_t)v[2], (bf16_t)v[3]};
                ((bf16x4*)Wb)[i] = o;
            }
        }
        return;
    }

    // ---------------- lora part ----------------
    const int kcn    = 1 << kshift;
    const int mchunk = bid >> kshift;
    const int kc     = bid & (kcn - 1);
    const int kspan  = K_DIM >> kshift;          // K per block
    const int kbeg   = kc * kspan;

    const int wave = tid >> 6;
    const int lane = tid & 63;
    const int bm0  = mchunk * 32;
    const int slot = mapping[bm0 >> 10];
    const float* __restrict__ A = lora_As + (size_t)slot * (K_DIM * 16);

    const int srow = tid >> 3;          // 0..31 staging row
    const int sc2  = tid & 7;           // chunk-pair 0..7
    const int r16  = lane & 15;
    const int kq   = lane >> 4;
    const int kk   = tid >> 1;          // A-tile k row 0..127
    const int half = tid & 1;

    f32x4 acc[2];
    acc[0] = (f32x4){0.f, 0.f, 0.f, 0.f};
    acc[1] = (f32x4){0.f, 0.f, 0.f, 0.f};

    const float* xrow = X + (size_t)(bm0 + srow) * K_DIM + sc2 * 16;

    // prefetch registers for first iteration
    f32x4 xv0 = *(const f32x4*)(xrow + kbeg);
    f32x4 xv1 = *(const f32x4*)(xrow + kbeg + 4);
    f32x4 xv2 = *(const f32x4*)(xrow + kbeg + 8);
    f32x4 xv3 = *(const f32x4*)(xrow + kbeg + 12);
    f32x4 av0 = *(const f32x4*)(A + (size_t)(kbeg + kk) * 16 + half * 8);
    f32x4 av1 = *(const f32x4*)(A + (size_t)(kbeg + kk) * 16 + half * 8 + 4);

    for (int k0 = kbeg; k0 < kbeg + kspan; k0 += 128) {
        bf16x8 c0 = {(bf16_t)xv0[0], (bf16_t)xv0[1], (bf16_t)xv0[2], (bf16_t)xv0[3],
                     (bf16_t)xv1[0], (bf16_t)xv1[1], (bf16_t)xv1[2], (bf16_t)xv1[3]};
        bf16x8 c1 = {(bf16_t)xv2[0], (bf16_t)xv2[1], (bf16_t)xv2[2], (bf16_t)xv2[3],
                     (bf16_t)xv3[0], (bf16_t)xv3[1], (bf16_t)xv3[2], (bf16_t)xv3[3]};
        if (Xb) {
            bf16x8* xbp = (bf16x8*)(Xb + (size_t)(bm0 + srow) * K_DIM + k0 + sc2 * 16);
            xbp[0] = c0;
            xbp[1] = c1;
        }
        const int k8a = sc2 * 2, k8b = sc2 * 2 + 1;
        *(bf16x8*)(Xt + (srow * 16 + (k8a ^ (srow & 15))) * 8) = c0;
        *(bf16x8*)(Xt + (srow * 16 + (k8b ^ (srow & 15))) * 8) = c1;

#pragma unroll
        for (int rr = 0; rr < 4; ++rr) {
            At[(half * 8 + rr) * 136 + kk]     = (bf16_t)av0[rr];
            At[(half * 8 + 4 + rr) * 136 + kk] = (bf16_t)av1[rr];
        }
        __syncthreads();

        // issue next iteration's global loads (overlap with MFMA phase)
        if (k0 + 128 < kbeg + kspan) {
            const float* xp = xrow + k0 + 128;
            xv0 = *(const f32x4*)(xp);
            xv1 = *(const f32x4*)(xp + 4);
            xv2 = *(const f32x4*)(xp + 8);
            xv3 = *(const f32x4*)(xp + 12);
            const float* ap = A + (size_t)(k0 + 128 + kk) * 16 + half * 8;
            av0 = *(const f32x4*)ap;
            av1 = *(const f32x4*)(ap + 4);
        }

#pragma unroll
        for (int i = 0; i < 2; ++i) {
            const int row_l = i * 16 + r16;
            const int c = wave * 4 + kq;
            bf16x8 af  = *(const bf16x8*)(Xt + (row_l * 16 + (c ^ (row_l & 15))) * 8);
            bf16x8 bfr = *(const bf16x8*)(At + r16 * 136 + wave * 32 + kq * 8);
            acc[i] = __builtin_amdgcn_mfma_f32_16x16x32_bf16(af, bfr, acc[i], 0, 0, 0);
        }
        __syncthreads();
    }

    // cross-wave reduction
#pragma unroll
    for (int i = 0; i < 2; ++i)
#pragma unroll
        for (int e = 0; e < 4; ++e)
            hred[wave * 512 + i * 256 + (kq * 4 + e) * 16 + r16] = acc[i][e];
    __syncthreads();
    float* hout = h_ws + (size_t)kc * (M_DIM * 16);
#pragma unroll
    for (int q = 0; q < 2; ++q) {
        const int entry = tid * 2 + q;          // 0..511
        const int row_l = entry >> 4, col = entry & 15;
        const int i = row_l >> 4, rr = row_l & 15;
        const int off = i * 256 + rr * 16 + col;
        float s = hred[off] + hred[512 + off] + hred[1024 + off] + hred[1536 + off];
        hout[(size_t)(bm0 + row_l) * 16 + col] = s * SCALE_F;
    }
}

// ---- shared epilogue: sum h partials + fused LoRA MFMA + bias + store ----
__device__ __forceinline__ void epilogue(
    f32x4 (&acc)[4][4], const float* __restrict__ bias,
    const float* __restrict__ lora_Bs, const int* __restrict__ mapping,
    const float* __restrict__ h_ws, int kcn, float* __restrict__ out,
    int bm0, int bn0, int wm0, int wn0, int r16, int kq)
{
    const int slot = mapping[bm0 >> 10];
    const bool hasK = (kq < 2);
    const int kq2 = hasK ? kq : 0;

    bf16x8 hfrag[4], bmf[4];
#pragma unroll
    for (int i = 0; i < 4; ++i) {
        const float* hp = h_ws + (size_t)(bm0 + wm0 + i * 16 + r16) * 16 + kq2 * 8;
        f32x4 h0 = *(const f32x4*)hp;
        f32x4 h1 = *(const f32x4*)(hp + 4);
        for (int c = 1; c < kcn; ++c) {
            const float* hq = hp + (size_t)c * (M_DIM * 16);
            h0 += *(const f32x4*)hq;
            h1 += *(const f32x4*)(hq + 4);
        }
#pragma unroll
        for (int jj = 0; jj < 4; ++jj) {
            hfrag[i][jj]     = hasK ? (bf16_t)h0[jj] : (bf16_t)0.f;
            hfrag[i][jj + 4] = hasK ? (bf16_t)h1[jj] : (bf16_t)0.f;
        }
    }
#pragma unroll
    for (int j = 0; j < 4; ++j) {
        const int o = bn0 + wn0 + j * 16 + r16;
#pragma unroll
        for (int jj = 0; jj < 8; ++jj) {
            const int r = kq2 * 8 + jj;
            const float v = lora_Bs[((size_t)slot * 16 + r) * N_DIM + o];
            bmf[j][jj] = hasK ? (bf16_t)v : (bf16_t)0.f;
        }
    }
#pragma unroll
    for (int i = 0; i < 4; ++i)
#pragma unroll
        for (int j = 0; j < 4; ++j)
            acc[i][j] = __builtin_amdgcn_mfma_f32_16x16x32_bf16(hfrag[i], bmf[j], acc[i][j], 0, 0, 0);

#pragma unroll
    for (int j = 0; j < 4; ++j) {
        const int o = bn0 + wn0 + j * 16 + r16;
        const float bv = bias[o];
#pragma unroll
        for (int i = 0; i < 4; ++i) {
#pragma unroll
            for (int e = 0; e < 4; ++e) {
                const int m = bm0 + wm0 + i * 16 + kq * 4 + e;
                out[(size_t)m * N_DIM + o] = acc[i][j][e] + bv;
            }
        }
    }
}

// ------------- main GEMM (R5 structure, 1024-block half-grid, m_base) -------------
__global__ __launch_bounds__(256) void gemm_lora_direct(
    const bf16_t* __restrict__ Xb, const bf16_t* __restrict__ Wb,
    const float* __restrict__ bias, const float* __restrict__ lora_Bs,
    const int* __restrict__ mapping, const float* __restrict__ h_ws, int kcn,
    float* __restrict__ out, int m_base)
{
    __shared__ bf16_t As[128 * 64];   // 16 KB
    __shared__ bf16_t Bs[128 * 64];   // 16 KB

    const int tid  = threadIdx.x;
    const int wave = tid >> 6;
    const int lane = tid & 63;
    const int bid  = blockIdx.x;
    const int n_t  = (bid & 7) + ((bid >> 8) << 3);  // 0..31 (XCD-aware)
    const int m_t  = ((bid >> 3) & 31) + m_base;     // 0..63
    const int bm0 = m_t * 128;
    const int bn0 = n_t * 128;
    const int wm0 = (wave >> 1) * 64;
    const int wn0 = (wave & 1) * 64;
    const int r16 = lane & 15;
    const int kq  = lane >> 4;

    f32x4 acc[4][4];
#pragma unroll
    for (int i = 0; i < 4; ++i)
#pragma unroll
        for (int j = 0; j < 4; ++j) acc[i][j] = (f32x4){0.f, 0.f, 0.f, 0.f};

    for (int k0 = 0; k0 < K_DIM; k0 += 64) {
#pragma unroll
        for (int p = 0; p < 4; ++p) {
            const int base = wave * 256 + p * 64;    // wave-uniform LDS slot base
            const int s    = base + lane;
            const int row  = s >> 3;
            const int k8g  = (s & 7) ^ (row & 7);
            gload_lds16(Xb + (size_t)(bm0 + row) * K_DIM + k0 + k8g * 8,
                        As + (size_t)base * 8);
            gload_lds16(Wb + (size_t)(bn0 + row) * K_DIM + k0 + k8g * 8,
                        Bs + (size_t)base * 8);
        }
        __syncthreads();

#pragma unroll
        for (int kh = 0; kh < 2; ++kh) {
            bf16x8 af[4], bfr[4];
            const int k8 = kh * 4 + kq;
#pragma unroll
            for (int i = 0; i < 4; ++i) {
                const int ra = wm0 + i * 16 + r16;
                const int rb = wn0 + i * 16 + r16;
                af[i]  = *(const bf16x8*)(As + ((size_t)ra * 8 + (k8 ^ (ra & 7))) * 8);
                bfr[i] = *(const bf16x8*)(Bs + ((size_t)rb * 8 + (k8 ^ (rb & 7))) * 8);
            }
#pragma unroll
            for (int i = 0; i < 4; ++i)
#pragma unroll
                for (int j = 0; j < 4; ++j)
                    acc[i][j] = __builtin_amdgcn_mfma_f32_16x16x32_bf16(af[i], bfr[j], acc[i][j], 0, 0, 0);
        }
        __syncthreads();
    }

    epilogue(acc, bias, lora_Bs, mapping, h_ws, kcn, out, bm0, bn0, wm0, wn0, r16, kq);
}

// ---------------- fallback: fp32 staging via global_load_lds, BK=32 ----------------
__global__ __launch_bounds__(256) void gemm_lora_f32s(
    const float* __restrict__ Xf, const float* __restrict__ Wf,
    const float* __restrict__ bias, const float* __restrict__ lora_Bs,
    const int* __restrict__ mapping, const float* __restrict__ h_ws,
    float* __restrict__ out)
{
    __shared__ float Asf[128 * 32];
    __shared__ float Bsf[128 * 32];

    const int tid  = threadIdx.x;
    const int wave = tid >> 6;
    const int lane = tid & 63;
    const int bid  = blockIdx.x;
    const int n_t  = (bid & 7) + ((bid >> 9) << 3);
    const int m_t  = (bid >> 3) & 63;
    const int bm0 = m_t * 128;
    const int bn0 = n_t * 128;
    const int wm0 = (wave >> 1) * 64;
    const int wn0 = (wave & 1) * 64;
    const int r16 = lane & 15;
    const int kq  = lane >> 4;

    f32x4 acc[4][4];
#pragma unroll
    for (int i = 0; i < 4; ++i)
#pragma unroll
        for (int j = 0; j < 4; ++j) acc[i][j] = (f32x4){0.f, 0.f, 0.f, 0.f};

    for (int k0 = 0; k0 < K_DIM; k0 += 32) {
#pragma unroll
        for (int p = 0; p < 4; ++p) {
            const int idx0 = (p * 4 + wave) * 64;
            const int idx  = idx0 + lane;
            const int k4   = idx >> 7;
            const int row  = idx & 127;
            gload_lds16(Xf + (size_t)(bm0 + row) * K_DIM + (k0 + k4 * 4),
                        Asf + (size_t)idx0 * 4);
            gload_lds16(Wf + (size_t)(bn0 + row) * K_DIM + (k0 + k4 * 4),
                        Bsf + (size_t)idx0 * 4);
        }
        __syncthreads();

        bf16x8 af[4], bfr[4];
#pragma unroll
        for (int i = 0; i < 4; ++i) {
            const int ra = wm0 + i * 16 + r16;
            const int rb = wn0 + i * 16 + r16;
            f32x4 a0 = *(const f32x4*)(Asf + ((size_t)(kq * 2) * 128 + ra) * 4);
            f32x4 a1 = *(const f32x4*)(Asf + ((size_t)(kq * 2 + 1) * 128 + ra) * 4);
            f32x4 b0 = *(const f32x4*)(Bsf + ((size_t)(kq * 2) * 128 + rb) * 4);
            f32x4 b1 = *(const f32x4*)(Bsf + ((size_t)(kq * 2 + 1) * 128 + rb) * 4);
            af[i]  = (bf16x8){(bf16_t)a0[0], (bf16_t)a0[1], (bf16_t)a0[2], (bf16_t)a0[3],
                              (bf16_t)a1[0], (bf16_t)a1[1], (bf16_t)a1[2], (bf16_t)a1[3]};
            bfr[i] = (bf16x8){(bf16_t)b0[0], (bf16_t)b0[1], (bf16_t)b0[2], (bf16_t)b0[3],
                              (bf16_t)b1[0], (bf16_t)b1[1], (bf16_t)b1[2], (bf16_t)b1[3]};
        }
#pragma unroll
        for (int i = 0; i < 4; ++i)
#pragma unroll
            for (int j = 0; j < 4; ++j)
                acc[i][j] = __builtin_amdgcn_mfma_f32_16x16x32_bf16(af[i], bfr[j], acc[i][j], 0, 0, 0);
        __syncthreads();
    }

    epilogue(acc, bias, lora_Bs, mapping, h_ws, 1, out, bm0, bn0, wm0, wn0, r16, kq);
}

extern "C" void kernel_launch(void* const* d_in, const int* in_sizes, int n_in,
                              void* d_out, int out_size, void* d_ws, size_t ws_size,
                              hipStream_t stream) {
    const float* x        = (const float*)d_in[0];
    const int*   mapping  = (const int*)d_in[1];
    const float* W        = (const float*)d_in[2];
    const float* b        = (const float*)d_in[3];
    const float* lora_As  = (const float*)d_in[4];
    const float* lora_Bs  = (const float*)d_in[5];
    float* out = (float*)d_out;

    const size_t xb_bytes = (size_t)M_DIM * K_DIM * 2;   // 64 MB
    const size_t wb_bytes = (size_t)N_DIM * K_DIM * 2;   // 32 MB
    const size_t h_bytes  = (size_t)M_DIM * 16 * 4;      // 512 KB per slice
    const bool direct4 = ws_size >= xb_bytes + wb_bytes + 4 * h_bytes;
    const bool direct1 = ws_size >= xb_bytes + wb_bytes + h_bytes;

    bf16_t* Xb = (bf16_t*)d_ws;
    bf16_t* Wb = (bf16_t*)((char*)d_ws + xb_bytes);

    if (direct4 || direct1) {
        const int kshift = direct4 ? 2 : 0;
        const int kcn    = 1 << kshift;
        const int lora_blocks = 256 * kcn;
        float* h_ws = (float*)((char*)d_ws + xb_bytes + wb_bytes);

        prep_kernel<<<dim3(lora_blocks + CVT_BLOCKS), 256, 0, stream>>>(
            x, lora_As, mapping, h_ws, Xb, W, Wb, lora_blocks, kshift);
        gemm_lora_direct<<<dim3(1024), 256, 0, stream>>>(
            Xb, Wb, b, lora_Bs, mapping, h_ws, kcn, out, 0);
        gemm_lora_direct<<<dim3(1024), 256, 0, stream>>>(
            Xb, Wb, b, lora_Bs, mapping, h_ws, kcn, out, 32);
    } else {
        float* h_ws = (float*)d_ws;
        prep_kernel<<<dim3(256 + CVT_BLOCKS), 256, 0, stream>>>(
            x, lora_As, mapping, h_ws, nullptr, W, nullptr, 256, 0);
        gemm_lora_f32s<<<dim3(2048), 256, 0, stream>>>(
            x, W, b, lora_Bs, mapping, h_ws, out);
    }
}